// Round 2
// baseline (1145.017 us; speedup 1.0000x reference)
//
#include <hip/hip_runtime.h>
#include <hip/hip_bf16.h>
#include <cstdint>

#define DEVINL __device__ __forceinline__

using f32x4  = __attribute__((ext_vector_type(4))) float;
using short8 = __attribute__((ext_vector_type(8))) short;
using short4v = __attribute__((ext_vector_type(4))) short;

DEVINL float bf2f(__hip_bfloat16 h){ return __bfloat162float(h); }
DEVINL __hip_bfloat16 f2bf(float f){ return __float2bfloat16(f); }
DEVINL short bfbits(float f){ __hip_bfloat16 h = __float2bfloat16(f); short s; __builtin_memcpy(&s, &h, 2); return s; }
DEVINL float sb2f(short s){ uint32_t u = ((uint32_t)(uint16_t)s) << 16; float f; __builtin_memcpy(&f, &u, 4); return f; }

DEVINL void gl_lds16(const void* g, void* l){
  __builtin_amdgcn_global_load_lds((const __attribute__((address_space(1))) void*)g,
                                   (__attribute__((address_space(3))) void*)l, 16, 0, 0);
}

// ---------------- weight transpose + f32->bf16 cast: dst[C][R] = src[R][C] ----------------
__global__ __launch_bounds__(256) void wtrans(const float* __restrict__ src,
                                              __hip_bfloat16* __restrict__ dst,
                                              int R, int C){
  __shared__ float tile[32][33];
  const int tr0 = blockIdx.y*32, tc0 = blockIdx.x*32;
  const int t = threadIdx.x;
  const int lr = t >> 3, lc = (t & 7) * 4;
  float4 v = *(const float4*)(src + (size_t)(tr0+lr)*C + tc0 + lc);
  tile[lr][lc] = v.x; tile[lr][lc+1] = v.y; tile[lr][lc+2] = v.z; tile[lr][lc+3] = v.w;
  __syncthreads();
  short4v o;
  o[0] = bfbits(tile[lc+0][lr]);
  o[1] = bfbits(tile[lc+1][lr]);
  o[2] = bfbits(tile[lc+2][lr]);
  o[3] = bfbits(tile[lc+3][lr]);
  *(short4v*)(dst + (size_t)(tc0+lr)*R + tr0 + lc) = o;
}

// ---------------- LayerNorm (C=2048), one row per block, bf16 out ----------------
__global__ __launch_bounds__(256) void ln_k(const float* __restrict__ x,
                                            const float* __restrict__ w,
                                            const float* __restrict__ bia,
                                            __hip_bfloat16* __restrict__ out){
  const int row = blockIdx.x, t = threadIdx.x;
  const float* xr = x + (size_t)row*2048;
  float4 v0 = *(const float4*)(xr + t*4);
  float4 v1 = *(const float4*)(xr + 1024 + t*4);
  float s  = v0.x+v0.y+v0.z+v0.w + v1.x+v1.y+v1.z+v1.w;
  float ss = v0.x*v0.x+v0.y*v0.y+v0.z*v0.z+v0.w*v0.w
           + v1.x*v1.x+v1.y*v1.y+v1.z*v1.z+v1.w*v1.w;
  #pragma unroll
  for (int o=1;o<64;o<<=1){ s += __shfl_xor(s,o); ss += __shfl_xor(ss,o); }
  __shared__ float red[8];
  const int wv = t>>6, ln = t&63;
  if (ln==0){ red[wv]=s; red[4+wv]=ss; }
  __syncthreads();
  s = red[0]+red[1]+red[2]+red[3]; ss = red[4]+red[5]+red[6]+red[7];
  const float mu = s*(1.f/2048.f);
  const float inv = rsqrtf(ss*(1.f/2048.f) - mu*mu + 1e-5f);
  {
    float4 wv4 = *(const float4*)(w + t*4);
    float4 bv4 = *(const float4*)(bia + t*4);
    short4v o;
    o[0]=bfbits((v0.x-mu)*inv*wv4.x + bv4.x);
    o[1]=bfbits((v0.y-mu)*inv*wv4.y + bv4.y);
    o[2]=bfbits((v0.z-mu)*inv*wv4.z + bv4.z);
    o[3]=bfbits((v0.w-mu)*inv*wv4.w + bv4.w);
    *(short4v*)(out + (size_t)row*2048 + t*4) = o;
  }
  {
    float4 wv4 = *(const float4*)(w + 1024 + t*4);
    float4 bv4 = *(const float4*)(bia + 1024 + t*4);
    short4v o;
    o[0]=bfbits((v1.x-mu)*inv*wv4.x + bv4.x);
    o[1]=bfbits((v1.y-mu)*inv*wv4.y + bv4.y);
    o[2]=bfbits((v1.z-mu)*inv*wv4.z + bv4.z);
    o[3]=bfbits((v1.w-mu)*inv*wv4.w + bv4.w);
    *(short4v*)(out + (size_t)row*2048 + 1024 + t*4) = o;
  }
}

// ---------------- GEMM: C[M,N] = A[M,K] * Bt[N,K]^T  (bf16 in, fused epilogues) ----------
// EPI 0: f32   1: f32 + resid (in-place ok)   2: silu->bf16   3: *emul->bf16 (in-place ok)
// EPI 4: plain bf16
template<int EPI>
__global__ __launch_bounds__(256) void gemm_bt(
    const __hip_bfloat16* __restrict__ A,
    const __hip_bfloat16* __restrict__ Bt,
    float* __restrict__ Cf,
    __hip_bfloat16* __restrict__ Cb,
    const float* __restrict__ resid,
    const __hip_bfloat16* __restrict__ emul,
    int M, int N, int K)
{
  __shared__ __hip_bfloat16 sm[8192];   // A tile [128][32] @0, B tile [128][32] @4096
  const int tid = threadIdx.x;
  const int lane = tid & 63, wave = tid >> 6;
  const int row0 = blockIdx.y*128, col0 = blockIdx.x*128;
  const int wm = wave >> 1, wn = wave & 1;
  f32x4 acc[4][4] = {};

  const __hip_bfloat16* gb[4];
  __hip_bfloat16* lb[4];
  #pragma unroll
  for (int i=0;i<4;i++){
    int c = (i*4+wave)*64 + lane;
    lb[i] = sm + c*8;
    if (c < 512) gb[i] = A + (size_t)(row0 + (c>>2))*K + (c&3)*8;
    else { int c2 = c - 512; gb[i] = Bt + (size_t)(col0 + (c2>>2))*K + (c2&3)*8; }
  }

  for (int kt=0; kt<K; kt+=32){
    #pragma unroll
    for (int i=0;i<4;i++) gl_lds16(gb[i] + kt, lb[i]);
    __syncthreads();
    short8 af[4], bfv[4];
    #pragma unroll
    for (int m=0;m<4;m++)
      af[m] = *(const short8*)(sm + (wm*64 + m*16 + (lane&15))*32 + (lane>>4)*8);
    #pragma unroll
    for (int n=0;n<4;n++)
      bfv[n] = *(const short8*)(sm + 4096 + (wn*64 + n*16 + (lane&15))*32 + (lane>>4)*8);
    #pragma unroll
    for (int m=0;m<4;m++)
      #pragma unroll
      for (int n=0;n<4;n++)
        acc[m][n] = __builtin_amdgcn_mfma_f32_16x16x32_bf16(af[m], bfv[n], acc[m][n], 0, 0, 0);
    __syncthreads();
  }

  #pragma unroll
  for (int m=0;m<4;m++){
    const int r0 = row0 + wm*64 + m*16 + ((lane>>4)<<2);
    #pragma unroll
    for (int n=0;n<4;n++){
      const int c = col0 + wn*64 + n*16 + (lane&15);
      #pragma unroll
      for (int j=0;j<4;j++){
        const size_t idx = (size_t)(r0 + j)*N + c;
        const float v = acc[m][n][j];
        if constexpr (EPI==0) Cf[idx] = v;
        else if constexpr (EPI==1) Cf[idx] = v + resid[idx];
        else if constexpr (EPI==2) { Cb[idx] = f2bf(v / (1.f + __expf(-v))); }
        else if constexpr (EPI==3) { Cb[idx] = f2bf(v * bf2f(emul[idx])); }
        else { Cb[idx] = f2bf(v); }
      }
    }
  }
}

// ------ RoPE + pack: qkv bf16 (B,T,3C) -> Q,K (BH,T,128) bf16, Vt (BH,128,T) bf16 ------
__global__ __launch_bounds__(256) void ropepack(
    const __hip_bfloat16* __restrict__ qkv, const float* __restrict__ cosT, const float* __restrict__ sinT,
    __hip_bfloat16* __restrict__ Qo, __hip_bfloat16* __restrict__ Ko, __hip_bfloat16* __restrict__ Vo)
{
  __shared__ short vt[128][72];
  const int bh = blockIdx.y, b = bh>>4, h = bh&15;
  const int t0 = blockIdx.x*64, tid = threadIdx.x;
  const int tr = tid>>2, q4 = tid&3;
  const int tg = t0 + tr;
  const __hip_bfloat16* base = qkv + ((size_t)(b*2048 + tg))*6144 + h*128;
  const int pp0 = q4*16;                // 16 rotary pairs per thread
  float cs[16], sn[16];
  #pragma unroll
  for (int i=0;i<4;i++){
    float4 c4 = *(const float4*)(cosT + (size_t)tg*64 + pp0 + i*4);
    float4 s4 = *(const float4*)(sinT + (size_t)tg*64 + pp0 + i*4);
    cs[i*4+0]=c4.x; cs[i*4+1]=c4.y; cs[i*4+2]=c4.z; cs[i*4+3]=c4.w;
    sn[i*4+0]=s4.x; sn[i*4+1]=s4.y; sn[i*4+2]=s4.z; sn[i*4+3]=s4.w;
  }
  #pragma unroll
  for (int qk=0; qk<2; ++qk){
    const __hip_bfloat16* src = base + qk*2048;
    __hip_bfloat16* dst = (qk==0 ? Qo : Ko) + ((size_t)bh*2048 + tg)*128 + pp0*2;
    short8 ov[4];
    short* o = (short*)ov;
    #pragma unroll
    for (int i=0;i<4;i++){
      short8 v = *(const short8*)(src + pp0*2 + i*8);
      #pragma unroll
      for (int j=0;j<4;j++){
        float xe = sb2f(v[2*j]), xo = sb2f(v[2*j+1]);
        float c = cs[4*i+j], s = sn[4*i+j];
        o[8*i+2*j]   = bfbits(xe*c - xo*s);
        o[8*i+2*j+1] = bfbits(xe*s + xo*c);
      }
    }
    #pragma unroll
    for (int i=0;i<4;i++) *(short8*)(dst + i*8) = ov[i];
  }
  // V transpose via LDS
  const __hip_bfloat16* vsrc = base + 4096;
  const int vc0 = q4*32;
  #pragma unroll
  for (int i=0;i<4;i++){
    short8 v = *(const short8*)(vsrc + vc0 + i*8);
    #pragma unroll
    for (int j=0;j<8;j++) vt[vc0+i*8+j][tr] = v[j];
  }
  __syncthreads();
  const int d = tid>>1, th0 = (tid&1)*32;
  __hip_bfloat16* vdst = Vo + ((size_t)bh*128 + d)*2048 + t0 + th0;
  #pragma unroll
  for (int i=0;i<4;i++)
    *(short8*)(vdst + i*8) = *(const short8*)(&vt[d][th0 + i*8]);
}

// ---------------- Flash attention, causal, 4 waves x 32 q-rows, KV step 32 ----------------
__global__ __launch_bounds__(256) void attn_k(
    const __hip_bfloat16* __restrict__ Q,
    const __hip_bfloat16* __restrict__ K,
    const __hip_bfloat16* __restrict__ Vt,
    __hip_bfloat16* __restrict__ Y)
{
  __shared__ __hip_bfloat16 pls[4][32][40];
  const int bh = blockIdx.y, b = bh>>4, h = bh&15;
  const int tid = threadIdx.x, lane = tid&63, wave = tid>>6;
  const int qbase = blockIdx.x*128 + wave*32;
  const __hip_bfloat16* Qh = Q + (size_t)bh*2048*128;
  const __hip_bfloat16* Kh = K + (size_t)bh*2048*128;
  const __hip_bfloat16* Vh = Vt + (size_t)bh*128*2048;
  __hip_bfloat16 (*pl)[40] = pls[wave];
  const int l15 = lane & 15, l4 = lane >> 4;

  short8 qf[2][4];
  #pragma unroll
  for (int m=0;m<2;m++)
    #pragma unroll
    for (int kc=0;kc<4;kc++)
      qf[m][kc] = *(const short8*)(Qh + (size_t)(qbase + m*16 + l15)*128 + kc*32 + l4*8);

  f32x4 accO[2][8] = {};
  float mrow[2][4], lrow[2][4];
  #pragma unroll
  for (int m=0;m<2;m++)
    #pragma unroll
    for (int j=0;j<4;j++){ mrow[m][j] = -1e30f; lrow[m][j] = 0.f; }
  const float scale = 0.08838834764831845f;
  const int nsteps = qbase/32 + 1;

  for (int s=0;s<nsteps;++s){
    const int kv0 = s*32;
    const bool diag = (kv0 == qbase);
    f32x4 sc[2][2] = {};
    #pragma unroll
    for (int n=0;n<2;n++){
      short8 kf[4];
      #pragma unroll
      for (int kc=0;kc<4;kc++)
        kf[kc] = *(const short8*)(Kh + (size_t)(kv0 + n*16 + l15)*128 + kc*32 + l4*8);
      #pragma unroll
      for (int m=0;m<2;m++)
        #pragma unroll
        for (int kc=0;kc<4;kc++)
          sc[m][n] = __builtin_amdgcn_mfma_f32_16x16x32_bf16(qf[m][kc], kf[kc], sc[m][n], 0,0,0);
    }
    float alpha_[2][4];
    #pragma unroll
    for (int m=0;m<2;m++)
      #pragma unroll
      for (int j=0;j<4;j++){
        const int qr = 16*m + 4*l4 + j;   // row rel. to this wave's 32 rows
        float a0 = sc[m][0][j]*scale;
        float a1 = sc[m][1][j]*scale;
        if (diag){
          if (l15 > qr)      a0 = -1e30f;
          if (16 + l15 > qr) a1 = -1e30f;
        }
        float mx = fmaxf(a0, a1);
        #pragma unroll
        for (int o=1;o<16;o<<=1) mx = fmaxf(mx, __shfl_xor(mx, o));
        const float mn = fmaxf(mrow[m][j], mx);
        const float p0 = __expf(a0 - mn);
        const float p1 = __expf(a1 - mn);
        float sum = p0 + p1;
        #pragma unroll
        for (int o=1;o<16;o<<=1) sum += __shfl_xor(sum, o);
        const float al = __expf(mrow[m][j] - mn);
        lrow[m][j] = lrow[m][j]*al + sum;
        mrow[m][j] = mn;
        alpha_[m][j] = al;
        pl[qr][l15]    = f2bf(p0);
        pl[qr][16+l15] = f2bf(p1);
      }
    #pragma unroll
    for (int m=0;m<2;m++)
      #pragma unroll
      for (int db=0;db<8;db++)
        #pragma unroll
        for (int j=0;j<4;j++)
          accO[m][db][j] *= alpha_[m][j];
    asm volatile("s_waitcnt lgkmcnt(0)" ::: "memory");
    __builtin_amdgcn_sched_barrier(0);
    short8 pa[2];
    #pragma unroll
    for (int m=0;m<2;m++)
      pa[m] = *(const short8*)(&pl[m*16 + l15][l4*8]);
    #pragma unroll
    for (int db=0;db<8;db++){
      short8 vf = *(const short8*)(Vh + (size_t)(db*16 + l15)*2048 + kv0 + l4*8);
      #pragma unroll
      for (int m=0;m<2;m++)
        accO[m][db] = __builtin_amdgcn_mfma_f32_16x16x32_bf16(pa[m], vf, accO[m][db], 0,0,0);
    }
  }
  #pragma unroll
  for (int m=0;m<2;m++)
    #pragma unroll
    for (int db=0;db<8;db++)
      #pragma unroll
      for (int j=0;j<4;j++){
        const int tg = qbase + 16*m + 4*l4 + j;
        const int d  = 16*db + l15;
        Y[((size_t)b*2048 + tg)*2048 + h*128 + d] = f2bf(accO[m][db][j] / lrow[m][j]);
      }
}

// ---------------- launcher ----------------
extern "C" void kernel_launch(void* const* d_in, const int* in_sizes, int n_in,
                              void* d_out, int out_size, void* d_ws, size_t ws_size,
                              hipStream_t stream)
{
  const float* x    = (const float*)d_in[0];
  const float* cosT = (const float*)d_in[1];
  const float* sinT = (const float*)d_in[2];
  const float* ln1w = (const float*)d_in[3];
  const float* ln1b = (const float*)d_in[4];
  const float* ln2w = (const float*)d_in[5];
  const float* ln2b = (const float*)d_in[6];
  const float* Wqkv = (const float*)d_in[7];
  const float* Wo   = (const float*)d_in[8];
  const float* W1   = (const float*)d_in[9];
  const float* W2   = (const float*)d_in[10];
  const float* W3   = (const float*)d_in[11];
  float* out = (float*)d_out;

  // ---- workspace layout (total 144 MB) ----
  // [0,32M)    WT   : shared transposed-weight scratch (re-filled before each GEMM)
  // [32M,48M)  abf  : LN output bf16 (reused ln1/ln2)
  // [48M,96M)  qkvb : qkv bf16   | later: Yb [48M,64M) | later: sub [48M,112M)
  // [96M,112M) Qb ; [112M,128M) Kb ; [128M,144M) Vtb
  // x2 lives in d_out (f32, written by gemm-Wo, read by ln2 + final residual in-place)
  if (ws_size < 150994944) return;   // diagnostic: absmax==7.625 -> ws too small
  char* ws = (char*)d_ws;
  __hip_bfloat16* WT   = (__hip_bfloat16*)(ws);
  __hip_bfloat16* abf  = (__hip_bfloat16*)(ws + 33554432);
  __hip_bfloat16* qkvb = (__hip_bfloat16*)(ws + 50331648);
  __hip_bfloat16* Yb   = (__hip_bfloat16*)(ws + 50331648);
  __hip_bfloat16* sub  = (__hip_bfloat16*)(ws + 50331648);
  __hip_bfloat16* Qb   = (__hip_bfloat16*)(ws + 100663296);
  __hip_bfloat16* Kb   = (__hip_bfloat16*)(ws + 117440512);
  __hip_bfloat16* Vtb  = (__hip_bfloat16*)(ws + 134217728);
  float*          x2   = out;

  ln_k<<<4096,256,0,stream>>>(x, ln1w, ln1b, abf);
  wtrans<<<dim3(192,64),256,0,stream>>>(Wqkv, WT, 2048, 6144);
  gemm_bt<4><<<dim3(48,32),256,0,stream>>>(abf, WT, nullptr, qkvb, nullptr, nullptr, 4096, 6144, 2048);
  ropepack<<<dim3(32,32),256,0,stream>>>(qkvb, cosT, sinT, Qb, Kb, Vtb);
  attn_k<<<dim3(16,32),256,0,stream>>>(Qb, Kb, Vtb, Yb);
  wtrans<<<dim3(64,64),256,0,stream>>>(Wo, WT, 2048, 2048);
  gemm_bt<1><<<dim3(16,32),256,0,stream>>>(Yb, WT, x2, nullptr, x, nullptr, 4096, 2048, 2048);
  ln_k<<<4096,256,0,stream>>>(x2, ln2w, ln2b, abf);
  wtrans<<<dim3(256,64),256,0,stream>>>(W1, WT, 2048, 8192);
  gemm_bt<2><<<dim3(64,32),256,0,stream>>>(abf, WT, nullptr, sub, nullptr, nullptr, 4096, 8192, 2048);
  wtrans<<<dim3(256,64),256,0,stream>>>(W2, WT, 2048, 8192);
  gemm_bt<3><<<dim3(64,32),256,0,stream>>>(abf, WT, nullptr, sub, nullptr, sub, 4096, 8192, 2048);
  wtrans<<<dim3(64,256),256,0,stream>>>(W3, WT, 8192, 2048);
  gemm_bt<1><<<dim3(16,32),256,0,stream>>>(sub, WT, out, nullptr, x2, nullptr, 4096, 2048, 8192);
}

// Round 3
// 1018.152 us; speedup vs baseline: 1.1246x; 1.1246x over previous
//
#include <hip/hip_runtime.h>
#include <hip/hip_bf16.h>
#include <cstdint>

#define DEVINL __device__ __forceinline__

using f32x4  = __attribute__((ext_vector_type(4))) float;
using short8 = __attribute__((ext_vector_type(8))) short;
using short4v = __attribute__((ext_vector_type(4))) short;

DEVINL float bf2f(__hip_bfloat16 h){ return __bfloat162float(h); }
DEVINL __hip_bfloat16 f2bf(float f){ return __float2bfloat16(f); }
DEVINL short bfbits(float f){ __hip_bfloat16 h = __float2bfloat16(f); short s; __builtin_memcpy(&s, &h, 2); return s; }
DEVINL float sb2f(short s){ uint32_t u = ((uint32_t)(uint16_t)s) << 16; float f; __builtin_memcpy(&f, &u, 4); return f; }

DEVINL void gl_lds16(const void* g, void* l){
  __builtin_amdgcn_global_load_lds((const __attribute__((address_space(1))) void*)g,
                                   (__attribute__((address_space(3))) void*)l, 16, 0, 0);
}

// ---------------- weight transpose + f32->bf16 cast: dst[C][R] = src[R][C] ----------------
__global__ __launch_bounds__(256) void wtrans(const float* __restrict__ src,
                                              __hip_bfloat16* __restrict__ dst,
                                              int R, int C){
  __shared__ float tile[32][33];
  const int tr0 = blockIdx.y*32, tc0 = blockIdx.x*32;
  const int t = threadIdx.x;
  const int lr = t >> 3, lc = (t & 7) * 4;
  float4 v = *(const float4*)(src + (size_t)(tr0+lr)*C + tc0 + lc);
  tile[lr][lc] = v.x; tile[lr][lc+1] = v.y; tile[lr][lc+2] = v.z; tile[lr][lc+3] = v.w;
  __syncthreads();
  short4v o;
  o[0] = bfbits(tile[lc+0][lr]);
  o[1] = bfbits(tile[lc+1][lr]);
  o[2] = bfbits(tile[lc+2][lr]);
  o[3] = bfbits(tile[lc+3][lr]);
  *(short4v*)(dst + (size_t)(tc0+lr)*R + tr0 + lc) = o;
}

// ---------------- LayerNorm (C=2048), one row per block, bf16 out ----------------
__global__ __launch_bounds__(256) void ln_k(const float* __restrict__ x,
                                            const float* __restrict__ w,
                                            const float* __restrict__ bia,
                                            __hip_bfloat16* __restrict__ out){
  const int row = blockIdx.x, t = threadIdx.x;
  const float* xr = x + (size_t)row*2048;
  float4 v0 = *(const float4*)(xr + t*4);
  float4 v1 = *(const float4*)(xr + 1024 + t*4);
  float s  = v0.x+v0.y+v0.z+v0.w + v1.x+v1.y+v1.z+v1.w;
  float ss = v0.x*v0.x+v0.y*v0.y+v0.z*v0.z+v0.w*v0.w
           + v1.x*v1.x+v1.y*v1.y+v1.z*v1.z+v1.w*v1.w;
  #pragma unroll
  for (int o=1;o<64;o<<=1){ s += __shfl_xor(s,o); ss += __shfl_xor(ss,o); }
  __shared__ float red[8];
  const int wv = t>>6, ln = t&63;
  if (ln==0){ red[wv]=s; red[4+wv]=ss; }
  __syncthreads();
  s = red[0]+red[1]+red[2]+red[3]; ss = red[4]+red[5]+red[6]+red[7];
  const float mu = s*(1.f/2048.f);
  const float inv = rsqrtf(ss*(1.f/2048.f) - mu*mu + 1e-5f);
  {
    float4 wv4 = *(const float4*)(w + t*4);
    float4 bv4 = *(const float4*)(bia + t*4);
    short4v o;
    o[0]=bfbits((v0.x-mu)*inv*wv4.x + bv4.x);
    o[1]=bfbits((v0.y-mu)*inv*wv4.y + bv4.y);
    o[2]=bfbits((v0.z-mu)*inv*wv4.z + bv4.z);
    o[3]=bfbits((v0.w-mu)*inv*wv4.w + bv4.w);
    *(short4v*)(out + (size_t)row*2048 + t*4) = o;
  }
  {
    float4 wv4 = *(const float4*)(w + 1024 + t*4);
    float4 bv4 = *(const float4*)(bia + 1024 + t*4);
    short4v o;
    o[0]=bfbits((v1.x-mu)*inv*wv4.x + bv4.x);
    o[1]=bfbits((v1.y-mu)*inv*wv4.y + bv4.y);
    o[2]=bfbits((v1.z-mu)*inv*wv4.z + bv4.z);
    o[3]=bfbits((v1.w-mu)*inv*wv4.w + bv4.w);
    *(short4v*)(out + (size_t)row*2048 + 1024 + t*4) = o;
  }
}

// ======== 256x256 deep-pipelined GEMM: C[M,N] = A[M,K] * Bt[N,K]^T, bf16 out ========
// 8 waves (2Mx4N), BK=64, LDS 128KB double-buffered, T2 swizzle, counted vmcnt(8), setprio.
// EPI 4: plain bf16   2: silu->bf16   3: *emul->bf16 (in-place ok)
template<int EPI>
__global__ __launch_bounds__(512, 2) void gemm256(
    const __hip_bfloat16* __restrict__ A,
    const __hip_bfloat16* __restrict__ Bt,
    __hip_bfloat16* __restrict__ Cb,
    const __hip_bfloat16* __restrict__ emul,
    int M, int N, int K, int NTN)
{
  extern __shared__ char smem[];                 // 131072 B: buf0 @0, buf1 @65536; A @+0 (32KB), B @+32768
  const int tid = threadIdx.x, lane = tid & 63, wave = tid >> 6;
  const int l15 = lane & 15, l4 = lane >> 4;
  const int wm = wave >> 2, wn = wave & 3;

  // T1: bijective XCD chunk swizzle (gridDim.x % 8 == 0)
  const int nwg = gridDim.x;
  const int id  = blockIdx.x;
  const int swz = (id & 7) * (nwg >> 3) + (id >> 3);
  const int by = swz / NTN, bx = swz % NTN;
  const int row0 = by * 256, col0 = bx * 256;

  // staging: 8 gl_lds/tile/wave; LDS linear dest, inverse-swizzled global source
  const __hip_bfloat16* gptr[8];
  int ldsoff[8];
  #pragma unroll
  for (int s = 0; s < 8; ++s){
    const int ss = s & 3;
    const int r    = (ss >> 1)*128 + (ss & 1)*64 + (tid >> 3);   // row within 256-row tile
    const int colp = (tid & 7) * 16;                             // physical byte col (0..127)
    const int coll = colp ^ ((r & 7) << 4);                      // logical byte col
    if (s < 4) gptr[s] = A  + (size_t)(row0 + r)*K + (coll >> 1);
    else       gptr[s] = Bt + (size_t)(col0 + r)*K + (coll >> 1);
    ldsoff[s] = (s < 4 ? 0 : 32768) + (ss >> 1)*16384 + (ss & 1)*8192 + tid*16;
  }
  auto STAGE = [&](int bufc, int ktile){
    #pragma unroll
    for (int s = 0; s < 8; ++s)
      gl_lds16(gptr[s] + (size_t)ktile*64, smem + bufc + ldsoff[s]);
  };

  // fragment-read bases (swizzled)
  const int swzm = (l15 & 7) << 4;
  const int aRow = (wm*128 + l15) * 128;            // byte row base in A half
  const int bRow = 32768 + (wn*64 + l15) * 128;     // byte row base in B half
  const int colT0 = (0*64 + l4*16) ^ swzm;
  const int colT1 = (1*64 + l4*16) ^ swzm;

  f32x4 acc[8][4] = {};
  const int NT = K >> 6;

  STAGE(0, 0);
  STAGE(65536, 1);
  __builtin_amdgcn_sched_barrier(0);
  asm volatile("s_waitcnt vmcnt(8)" ::: "memory");   // tile 0 resident
  __builtin_amdgcn_s_barrier();
  __builtin_amdgcn_sched_barrier(0);

  for (int t = 0; t < NT; ++t){
    const int bufc = (t & 1) * 65536;
    #pragma unroll
    for (int ks = 0; ks < 2; ++ks){
      const int ct = (ks == 0) ? colT0 : colT1;
      short8 a[8], b[4];
      #pragma unroll
      for (int m = 0; m < 8; ++m) a[m] = *(const short8*)(smem + bufc + aRow + m*2048 + ct);
      #pragma unroll
      for (int n = 0; n < 4; ++n) b[n] = *(const short8*)(smem + bufc + bRow + n*2048 + ct);
      __builtin_amdgcn_s_setprio(1);
      #pragma unroll
      for (int m = 0; m < 8; ++m)
        #pragma unroll
        for (int n = 0; n < 4; ++n)
          acc[m][n] = __builtin_amdgcn_mfma_f32_16x16x32_bf16(a[m], b[n], acc[m][n], 0, 0, 0);
      __builtin_amdgcn_s_setprio(0);
    }
    __builtin_amdgcn_sched_barrier(0);
    __builtin_amdgcn_s_barrier();                 // all waves done reading buf[cur]
    __builtin_amdgcn_sched_barrier(0);
    if (t + 2 < NT){
      STAGE(bufc, t + 2);
      __builtin_amdgcn_sched_barrier(0);
      asm volatile("s_waitcnt vmcnt(8)" ::: "memory");   // tile t+1 resident, t+2 in flight
    } else {
      asm volatile("s_waitcnt vmcnt(0)" ::: "memory");
    }
    __builtin_amdgcn_s_barrier();
    __builtin_amdgcn_sched_barrier(0);
  }

  #pragma unroll
  for (int m = 0; m < 8; ++m){
    const int r0 = row0 + wm*128 + m*16 + l4*4;
    #pragma unroll
    for (int n = 0; n < 4; ++n){
      const int c = col0 + wn*64 + n*16 + l15;
      #pragma unroll
      for (int j = 0; j < 4; ++j){
        const size_t idx = (size_t)(r0 + j)*N + c;
        const float v = acc[m][n][j];
        if constexpr (EPI == 2)      Cb[idx] = f2bf(v / (1.f + __expf(-v)));
        else if constexpr (EPI == 3) Cb[idx] = f2bf(v * bf2f(emul[idx]));
        else                         Cb[idx] = f2bf(v);
      }
    }
  }
}

// ---------------- 128x128 GEMM (kept for N=2048 shapes): C = A * Bt^T ----------------
// EPI 0: f32   1: f32 + resid (in-place ok)   4: plain bf16
template<int EPI>
__global__ __launch_bounds__(256) void gemm_bt(
    const __hip_bfloat16* __restrict__ A,
    const __hip_bfloat16* __restrict__ Bt,
    float* __restrict__ Cf,
    __hip_bfloat16* __restrict__ Cb,
    const float* __restrict__ resid,
    int M, int N, int K)
{
  __shared__ __hip_bfloat16 sm[8192];   // A tile [128][32] @0, B tile [128][32] @4096
  const int tid = threadIdx.x;
  const int lane = tid & 63, wave = tid >> 6;
  const int row0 = blockIdx.y*128, col0 = blockIdx.x*128;
  const int wm = wave >> 1, wn = wave & 1;
  f32x4 acc[4][4] = {};

  const __hip_bfloat16* gb[4];
  __hip_bfloat16* lb[4];
  #pragma unroll
  for (int i=0;i<4;i++){
    int c = (i*4+wave)*64 + lane;
    lb[i] = sm + c*8;
    if (c < 512) gb[i] = A + (size_t)(row0 + (c>>2))*K + (c&3)*8;
    else { int c2 = c - 512; gb[i] = Bt + (size_t)(col0 + (c2>>2))*K + (c2&3)*8; }
  }

  for (int kt=0; kt<K; kt+=32){
    #pragma unroll
    for (int i=0;i<4;i++) gl_lds16(gb[i] + kt, lb[i]);
    __syncthreads();
    short8 af[4], bfv[4];
    #pragma unroll
    for (int m=0;m<4;m++)
      af[m] = *(const short8*)(sm + (wm*64 + m*16 + (lane&15))*32 + (lane>>4)*8);
    #pragma unroll
    for (int n=0;n<4;n++)
      bfv[n] = *(const short8*)(sm + 4096 + (wn*64 + n*16 + (lane&15))*32 + (lane>>4)*8);
    #pragma unroll
    for (int m=0;m<4;m++)
      #pragma unroll
      for (int n=0;n<4;n++)
        acc[m][n] = __builtin_amdgcn_mfma_f32_16x16x32_bf16(af[m], bfv[n], acc[m][n], 0, 0, 0);
    __syncthreads();
  }

  #pragma unroll
  for (int m=0;m<4;m++){
    const int r0 = row0 + wm*64 + m*16 + ((lane>>4)<<2);
    #pragma unroll
    for (int n=0;n<4;n++){
      const int c = col0 + wn*64 + n*16 + (lane&15);
      #pragma unroll
      for (int j=0;j<4;j++){
        const size_t idx = (size_t)(r0 + j)*N + c;
        const float v = acc[m][n][j];
        if constexpr (EPI==0) Cf[idx] = v;
        else if constexpr (EPI==1) Cf[idx] = v + resid[idx];
        else Cb[idx] = f2bf(v);
      }
    }
  }
}

// ------ RoPE + pack: qkv bf16 (B,T,3C) -> Q,K (BH,T,128) bf16, Vt (BH,128,T) bf16 ------
__global__ __launch_bounds__(256) void ropepack(
    const __hip_bfloat16* __restrict__ qkv, const float* __restrict__ cosT, const float* __restrict__ sinT,
    __hip_bfloat16* __restrict__ Qo, __hip_bfloat16* __restrict__ Ko, __hip_bfloat16* __restrict__ Vo)
{
  __shared__ short vt[128][72];
  const int bh = blockIdx.y, b = bh>>4, h = bh&15;
  const int t0 = blockIdx.x*64, tid = threadIdx.x;
  const int tr = tid>>2, q4 = tid&3;
  const int tg = t0 + tr;
  const __hip_bfloat16* base = qkv + ((size_t)(b*2048 + tg))*6144 + h*128;
  const int pp0 = q4*16;                // 16 rotary pairs per thread
  float cs[16], sn[16];
  #pragma unroll
  for (int i=0;i<4;i++){
    float4 c4 = *(const float4*)(cosT + (size_t)tg*64 + pp0 + i*4);
    float4 s4 = *(const float4*)(sinT + (size_t)tg*64 + pp0 + i*4);
    cs[i*4+0]=c4.x; cs[i*4+1]=c4.y; cs[i*4+2]=c4.z; cs[i*4+3]=c4.w;
    sn[i*4+0]=s4.x; sn[i*4+1]=s4.y; sn[i*4+2]=s4.z; sn[i*4+3]=s4.w;
  }
  #pragma unroll
  for (int qk=0; qk<2; ++qk){
    const __hip_bfloat16* src = base + qk*2048;
    __hip_bfloat16* dst = (qk==0 ? Qo : Ko) + ((size_t)bh*2048 + tg)*128 + pp0*2;
    short8 ov[4];
    short* o = (short*)ov;
    #pragma unroll
    for (int i=0;i<4;i++){
      short8 v = *(const short8*)(src + pp0*2 + i*8);
      #pragma unroll
      for (int j=0;j<4;j++){
        float xe = sb2f(v[2*j]), xo = sb2f(v[2*j+1]);
        float c = cs[4*i+j], s = sn[4*i+j];
        o[8*i+2*j]   = bfbits(xe*c - xo*s);
        o[8*i+2*j+1] = bfbits(xe*s + xo*c);
      }
    }
    #pragma unroll
    for (int i=0;i<4;i++) *(short8*)(dst + i*8) = ov[i];
  }
  // V transpose via LDS
  const __hip_bfloat16* vsrc = base + 4096;
  const int vc0 = q4*32;
  #pragma unroll
  for (int i=0;i<4;i++){
    short8 v = *(const short8*)(vsrc + vc0 + i*8);
    #pragma unroll
    for (int j=0;j<8;j++) vt[vc0+i*8+j][tr] = v[j];
  }
  __syncthreads();
  const int d = tid>>1, th0 = (tid&1)*32;
  __hip_bfloat16* vdst = Vo + ((size_t)bh*128 + d)*2048 + t0 + th0;
  #pragma unroll
  for (int i=0;i<4;i++)
    *(short8*)(vdst + i*8) = *(const short8*)(&vt[d][th0 + i*8]);
}

// ---------------- Flash attention, causal, 4 waves x 32 q-rows, KV step 32 ----------------
__global__ __launch_bounds__(256) void attn_k(
    const __hip_bfloat16* __restrict__ Q,
    const __hip_bfloat16* __restrict__ K,
    const __hip_bfloat16* __restrict__ Vt,
    __hip_bfloat16* __restrict__ Y)
{
  __shared__ __hip_bfloat16 pls[4][32][40];
  const int bh = blockIdx.y, b = bh>>4, h = bh&15;
  const int tid = threadIdx.x, lane = tid&63, wave = tid>>6;
  const int qbase = blockIdx.x*128 + wave*32;
  const __hip_bfloat16* Qh = Q + (size_t)bh*2048*128;
  const __hip_bfloat16* Kh = K + (size_t)bh*2048*128;
  const __hip_bfloat16* Vh = Vt + (size_t)bh*128*2048;
  __hip_bfloat16 (*pl)[40] = pls[wave];
  const int l15 = lane & 15, l4 = lane >> 4;

  short8 qf[2][4];
  #pragma unroll
  for (int m=0;m<2;m++)
    #pragma unroll
    for (int kc=0;kc<4;kc++)
      qf[m][kc] = *(const short8*)(Qh + (size_t)(qbase + m*16 + l15)*128 + kc*32 + l4*8);

  f32x4 accO[2][8] = {};
  float mrow[2][4], lrow[2][4];
  #pragma unroll
  for (int m=0;m<2;m++)
    #pragma unroll
    for (int j=0;j<4;j++){ mrow[m][j] = -1e30f; lrow[m][j] = 0.f; }
  const float scale = 0.08838834764831845f;
  const int nsteps = qbase/32 + 1;

  for (int s=0;s<nsteps;++s){
    const int kv0 = s*32;
    const bool diag = (kv0 == qbase);
    f32x4 sc[2][2] = {};
    #pragma unroll
    for (int n=0;n<2;n++){
      short8 kf[4];
      #pragma unroll
      for (int kc=0;kc<4;kc++)
        kf[kc] = *(const short8*)(Kh + (size_t)(kv0 + n*16 + l15)*128 + kc*32 + l4*8);
      #pragma unroll
      for (int m=0;m<2;m++)
        #pragma unroll
        for (int kc=0;kc<4;kc++)
          sc[m][n] = __builtin_amdgcn_mfma_f32_16x16x32_bf16(qf[m][kc], kf[kc], sc[m][n], 0,0,0);
    }
    float alpha_[2][4];
    #pragma unroll
    for (int m=0;m<2;m++)
      #pragma unroll
      for (int j=0;j<4;j++){
        const int qr = 16*m + 4*l4 + j;   // row rel. to this wave's 32 rows
        float a0 = sc[m][0][j]*scale;
        float a1 = sc[m][1][j]*scale;
        if (diag){
          if (l15 > qr)      a0 = -1e30f;
          if (16 + l15 > qr) a1 = -1e30f;
        }
        float mx = fmaxf(a0, a1);
        #pragma unroll
        for (int o=1;o<16;o<<=1) mx = fmaxf(mx, __shfl_xor(mx, o));
        const float mn = fmaxf(mrow[m][j], mx);
        const float p0 = __expf(a0 - mn);
        const float p1 = __expf(a1 - mn);
        float sum = p0 + p1;
        #pragma unroll
        for (int o=1;o<16;o<<=1) sum += __shfl_xor(sum, o);
        const float al = __expf(mrow[m][j] - mn);
        lrow[m][j] = lrow[m][j]*al + sum;
        mrow[m][j] = mn;
        alpha_[m][j] = al;
        pl[qr][l15]    = f2bf(p0);
        pl[qr][16+l15] = f2bf(p1);
      }
    #pragma unroll
    for (int m=0;m<2;m++)
      #pragma unroll
      for (int db=0;db<8;db++)
        #pragma unroll
        for (int j=0;j<4;j++)
          accO[m][db][j] *= alpha_[m][j];
    asm volatile("s_waitcnt lgkmcnt(0)" ::: "memory");
    __builtin_amdgcn_sched_barrier(0);
    short8 pa[2];
    #pragma unroll
    for (int m=0;m<2;m++)
      pa[m] = *(const short8*)(&pl[m*16 + l15][l4*8]);
    #pragma unroll
    for (int db=0;db<8;db++){
      short8 vf = *(const short8*)(Vh + (size_t)(db*16 + l15)*2048 + kv0 + l4*8);
      #pragma unroll
      for (int m=0;m<2;m++)
        accO[m][db] = __builtin_amdgcn_mfma_f32_16x16x32_bf16(pa[m], vf, accO[m][db], 0,0,0);
    }
  }
  #pragma unroll
  for (int m=0;m<2;m++)
    #pragma unroll
    for (int db=0;db<8;db++)
      #pragma unroll
      for (int j=0;j<4;j++){
        const int tg = qbase + 16*m + 4*l4 + j;
        const int d  = 16*db + l15;
        Y[((size_t)b*2048 + tg)*2048 + h*128 + d] = f2bf(accO[m][db][j] / lrow[m][j]);
      }
}

// ---------------- launcher ----------------
extern "C" void kernel_launch(void* const* d_in, const int* in_sizes, int n_in,
                              void* d_out, int out_size, void* d_ws, size_t ws_size,
                              hipStream_t stream)
{
  const float* x    = (const float*)d_in[0];
  const float* cosT = (const float*)d_in[1];
  const float* sinT = (const float*)d_in[2];
  const float* ln1w = (const float*)d_in[3];
  const float* ln1b = (const float*)d_in[4];
  const float* ln2w = (const float*)d_in[5];
  const float* ln2b = (const float*)d_in[6];
  const float* Wqkv = (const float*)d_in[7];
  const float* Wo   = (const float*)d_in[8];
  const float* W1   = (const float*)d_in[9];
  const float* W2   = (const float*)d_in[10];
  const float* W3   = (const float*)d_in[11];
  float* out = (float*)d_out;

  if (ws_size < 150994944) return;   // diagnostic: absmax==7.625 -> ws too small
  char* ws = (char*)d_ws;
  __hip_bfloat16* WT   = (__hip_bfloat16*)(ws);                  // [0,32M)
  __hip_bfloat16* abf  = (__hip_bfloat16*)(ws + 33554432);       // [32M,48M)
  __hip_bfloat16* qkvb = (__hip_bfloat16*)(ws + 50331648);       // [48M,96M)
  __hip_bfloat16* Yb   = (__hip_bfloat16*)(ws + 50331648);
  __hip_bfloat16* sub  = (__hip_bfloat16*)(ws + 50331648);       // [48M,112M) after attn
  __hip_bfloat16* Qb   = (__hip_bfloat16*)(ws + 100663296);
  __hip_bfloat16* Kb   = (__hip_bfloat16*)(ws + 117440512);
  __hip_bfloat16* Vtb  = (__hip_bfloat16*)(ws + 134217728);
  float*          x2   = out;

  // allow 128KB dynamic LDS for gemm256 (non-stream API; idempotent, capture-safe)
  hipFuncSetAttribute(reinterpret_cast<const void*>(&gemm256<4>),
                      hipFuncAttributeMaxDynamicSharedMemorySize, 131072);
  hipFuncSetAttribute(reinterpret_cast<const void*>(&gemm256<2>),
                      hipFuncAttributeMaxDynamicSharedMemorySize, 131072);
  hipFuncSetAttribute(reinterpret_cast<const void*>(&gemm256<3>),
                      hipFuncAttributeMaxDynamicSharedMemorySize, 131072);

  ln_k<<<4096,256,0,stream>>>(x, ln1w, ln1b, abf);
  wtrans<<<dim3(192,64),256,0,stream>>>(Wqkv, WT, 2048, 6144);
  gemm256<4><<<384,512,131072,stream>>>(abf, WT, qkvb, nullptr, 4096, 6144, 2048, 24);
  ropepack<<<dim3(32,32),256,0,stream>>>(qkvb, cosT, sinT, Qb, Kb, Vtb);
  attn_k<<<dim3(16,32),256,0,stream>>>(Qb, Kb, Vtb, Yb);
  wtrans<<<dim3(64,64),256,0,stream>>>(Wo, WT, 2048, 2048);
  gemm_bt<1><<<dim3(16,32),256,0,stream>>>(Yb, WT, x2, nullptr, x, 4096, 2048, 2048);
  ln_k<<<4096,256,0,stream>>>(x2, ln2w, ln2b, abf);
  wtrans<<<dim3(256,64),256,0,stream>>>(W1, WT, 2048, 8192);
  gemm256<2><<<512,512,131072,stream>>>(abf, WT, sub, nullptr, 4096, 8192, 2048, 32);
  wtrans<<<dim3(256,64),256,0,stream>>>(W2, WT, 2048, 8192);
  gemm256<3><<<512,512,131072,stream>>>(abf, WT, sub, sub, 4096, 8192, 2048, 32);
  wtrans<<<dim3(64,256),256,0,stream>>>(W3, WT, 8192, 2048);
  gemm_bt<1><<<dim3(16,32),256,0,stream>>>(sub, WT, out, nullptr, x2, 4096, 2048, 8192);
}